// Round 14
// baseline (372.389 us; speedup 1.0000x reference)
//
#include <hip/hip_runtime.h>
#include <hip/hip_bf16.h>

#define B_ 4
#define C_ 128
#define N_ 4096
#define M_ 4096

typedef __bf16 bf16;
typedef __bf16 bf16x8 __attribute__((ext_vector_type(8)));
typedef float f32x4 __attribute__((ext_vector_type(4)));

#define MFMA16(a, b, c) __builtin_amdgcn_mfma_f32_16x16x32_bf16(a, b, c, 0, 0, 0)

__device__ inline bf16x8 cvt8(const float* p8) {
    float4 a = *(const float4*)p8;
    float4 b = *(const float4*)(p8 + 4);
    bf16x8 r;
    r[0] = (bf16)a.x; r[1] = (bf16)a.y; r[2] = (bf16)a.z; r[3] = (bf16)a.w;
    r[4] = (bf16)b.x; r[5] = (bf16)b.y; r[6] = (bf16)b.z; r[7] = (bf16)b.w;
    return r;
}

// ===========================================================================
// Kernel 1: LDS-staged projections (fp32 in -> bf16 ws).
// grid.z: 0 = Q (x1,p1,Wq -> Qt[b][n][c]); 1 = K+V (x2,p2,Wk,Wv -> Kt, Vt)
//         -- x2 is read ONCE for both K and V (R13 read it twice).
// Stage 1: coalesced float4 x-tile loads (128c x 64n) + Wpos/p -> LDS.
// Stage 2: pos-fold in fp32, bf16 convert, write [n][c] LDS tiles (stride 136).
// Stage 3: MFMA, B-frags via ds_read_b128 (R13 used 32 scattered 4B gathers).
// ===========================================================================
__global__ __launch_bounds__(256, 4) void proj_kernel(
    const float* __restrict__ x1, const float* __restrict__ p1,
    const float* __restrict__ x2, const float* __restrict__ p2,
    const float* __restrict__ Wq, const float* __restrict__ Wk,
    const float* __restrict__ Wv, const float* __restrict__ Wpos,
    bf16* __restrict__ Qt, bf16* __restrict__ Kt, bf16* __restrict__ Vt) {
    __shared__ __align__(16) bf16 xp[64 * 136];   // x + pos, [n][c]
    __shared__ __align__(16) bf16 xr[64 * 136];   // raw x,   [n][c] (path 1)
    __shared__ float wls[384];                    // Wpos
    __shared__ float pp[3 * 64];                  // p chunk [k][n]

    const int path = blockIdx.z;
    const int b = blockIdx.y;
    const int n0 = blockIdx.x * 64;
    const int t = threadIdx.x;
    const int w = t >> 6;
    const int lane = t & 63;
    const int col = lane & 15, quad = lane >> 4;

    const float* x = path ? x2 : x1;
    const float* p = path ? p2 : p1;

    // ---- stage 1: issue coalesced x loads; stage Wpos/p into LDS ----
    float4 xreg[8];
    #pragma unroll
    for (int k = 0; k < 8; ++k) {
        int f = k * 256 + t;
        int c = f >> 4, nn = (f & 15) * 4;
        xreg[k] = *(const float4*)(x + ((size_t)b * C_ + c) * N_ + n0 + nn);
    }
    for (int i = t; i < 384; i += 256) wls[i] = Wpos[i];
    if (t < 48) {
        int k3 = t >> 4, i4 = (t & 15) * 4;
        *(float4*)&pp[k3 * 64 + i4] =
            *(const float4*)(p + ((size_t)b * 3 + k3) * N_ + n0 + i4);
    }
    __syncthreads();

    // ---- stage 2: pos-fold, convert, write LDS tiles ----
    #pragma unroll
    for (int k = 0; k < 8; ++k) {
        int f = k * 256 + t;
        int c = f >> 4, nn = (f & 15) * 4;
        float w0 = wls[c * 3 + 0], w1 = wls[c * 3 + 1], w2 = wls[c * 3 + 2];
        const float* xv = &xreg[k].x;
        #pragma unroll
        for (int j = 0; j < 4; ++j) {
            float pos = w0 * pp[nn + j] + w1 * pp[64 + nn + j] + w2 * pp[128 + nn + j];
            xp[(nn + j) * 136 + c] = (bf16)(xv[j] + pos);
            if (path) xr[(nn + j) * 136 + c] = (bf16)xv[j];
        }
    }
    __syncthreads();

    // ---- stage 3: MFMA. A = W row, B = x-tile from LDS ----
    const int nl = w * 16 + col;          // tile-local point index
    const int n = n0 + nl;
    bf16x8 bx[4];
    #pragma unroll
    for (int cs = 0; cs < 4; ++cs)
        bx[cs] = *(const bf16x8*)&xp[nl * 136 + cs * 32 + quad * 8];

    const float* Wm = path ? Wk : Wq;
    bf16* Ot = path ? Kt : Qt;
    #pragma unroll
    for (int dt = 0; dt < 8; ++dt) {
        f32x4 acc = {0.f, 0.f, 0.f, 0.f};
        #pragma unroll
        for (int cs = 0; cs < 4; ++cs) {
            bf16x8 wf = cvt8(Wm + (dt * 16 + col) * 128 + cs * 32 + quad * 8);
            acc = MFMA16(wf, bx[cs], acc);
        }
        union { ushort4 u4; bf16 h[4]; } pk;
        #pragma unroll
        for (int r = 0; r < 4; ++r) pk.h[r] = (bf16)acc[r];
        *(ushort4*)(Ot + ((size_t)b * N_ + n) * C_ + dt * 16 + quad * 4) = pk.u4;
    }

    if (path) {
        bf16x8 br[4];
        #pragma unroll
        for (int cs = 0; cs < 4; ++cs)
            br[cs] = *(const bf16x8*)&xr[nl * 136 + cs * 32 + quad * 8];
        #pragma unroll
        for (int dt = 0; dt < 8; ++dt) {
            f32x4 acc = {0.f, 0.f, 0.f, 0.f};
            #pragma unroll
            for (int cs = 0; cs < 4; ++cs) {
                bf16x8 wf = cvt8(Wv + (dt * 16 + col) * 128 + cs * 32 + quad * 8);
                acc = MFMA16(wf, br[cs], acc);
            }
            #pragma unroll
            for (int r = 0; r < 4; ++r)
                Vt[((size_t)b * C_ + dt * 16 + quad * 4 + r) * (size_t)M_ + n] = (bf16)acc[r];
        }
    }
}

// ===========================================================================
// Kernel 2: flash attention + residual. Grid (N/32, B); block 512 = 8 waves:
// band = w&1 (16 queries), quarter = w>>1 (1024 keys, 16 iters of 64).
// R14 changes vs R13 (which sat at MfmaUtil 5.7%, VGPR 56 -- reg-starved):
//   * __launch_bounds__(512,4): ~128-VGPR budget, still 2 blocks/CU.
//   * K loads batched 8-at-a-time into registers before their MFMAs.
//   * All 16 V loads issued BEFORE the exp/LDS phase (independent of P), so
//     V latency overlaps exp + LDS round-trip.
// P: MFMA C-layout -> wave-private LDS (stride 72) -> A-layout, lgkmcnt fence.
// End: 2-step LDS tree merge over the 4 quarters per band.
// ===========================================================================
__global__ __launch_bounds__(512, 4) void attn_kernel(
    const bf16* __restrict__ Qt, const bf16* __restrict__ Kt,
    const bf16* __restrict__ Vt, const float* __restrict__ x1,
    float* __restrict__ out) {
    __shared__ __align__(16) bf16 pbuf[8][16 * 72];
    __shared__ float obuf[4][16 * 132];
    __shared__ float lbuf[4][16];

    const int w = threadIdx.x >> 6;
    const int lane = threadIdx.x & 63;
    const int col = lane & 15, quad = lane >> 4;
    const int band = w & 1, q = w >> 1;
    const int b = blockIdx.y;
    const int n0 = blockIdx.x * 32;

    const float KS = 0.12752107168406815f;  // log2(e)/sqrt(128)

    bf16x8 qf[4];
    {
        const bf16* Qb = Qt + ((size_t)b * N_ + n0 + band * 16 + col) * C_;
        #pragma unroll
        for (int cs = 0; cs < 4; ++cs)
            qf[cs] = *(const bf16x8*)(Qb + cs * 32 + quad * 8);
    }

    f32x4 oacc[8];
    #pragma unroll
    for (int t = 0; t < 8; ++t) oacc[t] = (f32x4){0.f, 0.f, 0.f, 0.f};
    float lacc[4] = {0.f, 0.f, 0.f, 0.f};

    bf16* pb = pbuf[w];

    for (int it = 0; it < 16; ++it) {
        const int m0 = q * 1024 + it * 64;
        const bf16* Kb = Kt + ((size_t)b * M_ + m0) * C_;
        const bf16* Vb = Vt + (size_t)b * C_ * M_ + m0;

        // ---- S = Q K^T in two 8-fragment batches ----
        f32x4 sacc[4];
        #pragma unroll
        for (int ms = 0; ms < 4; ++ms) sacc[ms] = (f32x4){0.f, 0.f, 0.f, 0.f};
        #pragma unroll
        for (int h = 0; h < 2; ++h) {
            bf16x8 kf[8];
            #pragma unroll
            for (int ms = 0; ms < 2; ++ms)
                #pragma unroll
                for (int cs = 0; cs < 4; ++cs)
                    kf[ms * 4 + cs] = *(const bf16x8*)(
                        Kb + ((h * 2 + ms) * 16 + col) * C_ + cs * 32 + quad * 8);
            #pragma unroll
            for (int ms = 0; ms < 2; ++ms)
                #pragma unroll
                for (int cs = 0; cs < 4; ++cs)
                    sacc[h * 2 + ms] = MFMA16(qf[cs], kf[ms * 4 + cs], sacc[h * 2 + ms]);
        }

        // ---- issue ALL V loads now (independent of P) ----
        bf16x8 vfa[8], vfb[8];
        #pragma unroll
        for (int t = 0; t < 4; ++t)
            #pragma unroll
            for (int ks = 0; ks < 2; ++ks)
                vfa[t * 2 + ks] = *(const bf16x8*)(
                    Vb + (size_t)(t * 16 + col) * M_ + ks * 32 + quad * 8);
        #pragma unroll
        for (int t = 0; t < 4; ++t)
            #pragma unroll
            for (int ks = 0; ks < 2; ++ks)
                vfb[t * 2 + ks] = *(const bf16x8*)(
                    Vb + (size_t)((t + 4) * 16 + col) * M_ + ks * 32 + quad * 8);

        // ---- P = exp2(S*KS); row sums; stash in LDS (overlaps V latency) ----
        #pragma unroll
        for (int ms = 0; ms < 4; ++ms)
            #pragma unroll
            for (int r = 0; r < 4; ++r) {
                float e = fminf(sacc[ms][r] * KS, 60.f);
                float pvv = __builtin_amdgcn_exp2f(e);
                lacc[r] += pvv;
                pb[(quad * 4 + r) * 72 + ms * 16 + col] = (bf16)pvv;
            }
        asm volatile("s_waitcnt lgkmcnt(0)" ::: "memory");

        bf16x8 af0 = *(const bf16x8*)(pb + col * 72 + quad * 8);
        bf16x8 af1 = *(const bf16x8*)(pb + col * 72 + 32 + quad * 8);

        // ---- O += P V^T ----
        #pragma unroll
        for (int t = 0; t < 4; ++t) {
            oacc[t] = MFMA16(af0, vfa[t * 2 + 0], oacc[t]);
            oacc[t] = MFMA16(af1, vfa[t * 2 + 1], oacc[t]);
        }
        #pragma unroll
        for (int t = 0; t < 4; ++t) {
            oacc[t + 4] = MFMA16(af0, vfb[t * 2 + 0], oacc[t + 4]);
            oacc[t + 4] = MFMA16(af1, vfb[t * 2 + 1], oacc[t + 4]);
        }
    }

    // reduce row sums across the 16 key-columns
    #pragma unroll
    for (int r = 0; r < 4; ++r)
        #pragma unroll
        for (int off = 1; off < 16; off <<= 1)
            lacc[r] += __shfl_xor(lacc[r], off, 64);

    // ---- merge tree over quarters: (0+2), (1+3), then (01 + 23) ----
    if (q >= 2) {
        const int slot = band * 2 + (q - 2);
        #pragma unroll
        for (int t = 0; t < 8; ++t)
            #pragma unroll
            for (int r = 0; r < 4; ++r)
                obuf[slot][(quad * 4 + r) * 132 + t * 16 + col] = oacc[t][r];
        if (col == 0)
            #pragma unroll
            for (int r = 0; r < 4; ++r)
                lbuf[slot][quad * 4 + r] = lacc[r];
    }
    __syncthreads();
    if (q < 2) {
        const int slot = band * 2 + q;
        #pragma unroll
        for (int t = 0; t < 8; ++t)
            #pragma unroll
            for (int r = 0; r < 4; ++r)
                oacc[t][r] += obuf[slot][(quad * 4 + r) * 132 + t * 16 + col];
        #pragma unroll
        for (int r = 0; r < 4; ++r)
            lacc[r] += lbuf[slot][quad * 4 + r];
    }
    __syncthreads();
    if (q == 1) {
        const int slot = band * 2 + 1;
        #pragma unroll
        for (int t = 0; t < 8; ++t)
            #pragma unroll
            for (int r = 0; r < 4; ++r)
                obuf[slot][(quad * 4 + r) * 132 + t * 16 + col] = oacc[t][r];
        if (col == 0)
            #pragma unroll
            for (int r = 0; r < 4; ++r)
                lbuf[slot][quad * 4 + r] = lacc[r];
    }
    __syncthreads();
    if (q == 0) {
        const int slot = band * 2 + 1;
        float linv[4];
        #pragma unroll
        for (int r = 0; r < 4; ++r)
            linv[r] = 1.0f / (lacc[r] + lbuf[slot][quad * 4 + r]);
        #pragma unroll
        for (int t = 0; t < 8; ++t) {
            #pragma unroll
            for (int r = 0; r < 4; ++r) {
                int n = n0 + band * 16 + quad * 4 + r;
                int c = t * 16 + col;
                float o = (oacc[t][r] + obuf[slot][(quad * 4 + r) * 132 + t * 16 + col]) * linv[r];
                float xr = x1[((size_t)b * C_ + c) * N_ + n];
                out[((size_t)b * N_ + n) * C_ + c] = o + xr;
            }
        }
    }
}

// ---------------------------------------------------------------------------
extern "C" void kernel_launch(void* const* d_in, const int* in_sizes, int n_in,
                              void* d_out, int out_size, void* d_ws, size_t ws_size,
                              hipStream_t stream) {
    const float* x1   = (const float*)d_in[0];
    const float* p1   = (const float*)d_in[1];
    const float* x2   = (const float*)d_in[2];
    const float* p2   = (const float*)d_in[3];
    const float* Wq   = (const float*)d_in[4];
    const float* Wk   = (const float*)d_in[5];
    const float* Wv   = (const float*)d_in[6];
    const float* Wpos = (const float*)d_in[7];
    float* out = (float*)d_out;

    bf16* Qt = (bf16*)d_ws;                 // [B][N][C]
    bf16* Kt = Qt + (size_t)B_ * N_ * C_;   // [B][M][C]
    bf16* Vt = Kt + (size_t)B_ * M_ * C_;   // [B][C][M]

    proj_kernel<<<dim3(64, B_, 2), dim3(256), 0, stream>>>(
        x1, p1, x2, p2, Wq, Wk, Wv, Wpos, Qt, Kt, Vt);
    attn_kernel<<<dim3(N_ / 32, B_), dim3(512), 0, stream>>>(Qt, Kt, Vt, x1, out);
}

// Round 15
// 262.868 us; speedup vs baseline: 1.4166x; 1.4166x over previous
//
#include <hip/hip_runtime.h>
#include <hip/hip_bf16.h>

#define B_ 4
#define C_ 128
#define N_ 4096
#define M_ 4096

typedef __bf16 bf16;
typedef __bf16 bf16x8 __attribute__((ext_vector_type(8)));
typedef float f32x4 __attribute__((ext_vector_type(4)));

#define MFMA16(a, b, c) __builtin_amdgcn_mfma_f32_16x16x32_bf16(a, b, c, 0, 0, 0)

__device__ inline bf16x8 cvt8(const float* p8) {
    float4 a = *(const float4*)p8;
    float4 b = *(const float4*)(p8 + 4);
    bf16x8 r;
    r[0] = (bf16)a.x; r[1] = (bf16)a.y; r[2] = (bf16)a.z; r[3] = (bf16)a.w;
    r[4] = (bf16)b.x; r[5] = (bf16)b.y; r[6] = (bf16)b.z; r[7] = (bf16)b.w;
    return r;
}

// ===========================================================================
// Kernel 1: fused projections, one block per 64-point tile (grid 64 x B),
// 768 threads = 12 waves: role = w>>2 (0:Q 1:K 2:V), band = w&3 (16 points).
// Stage x1+x2 coalesced (float4) -> pos-fold -> bf16 [n][c] LDS tiles
// (stride 136); W fragments from global (L1-hot). 1 block/CU, 12 waves.
// ===========================================================================
__global__ __launch_bounds__(768) void proj_kernel(
    const float* __restrict__ x1, const float* __restrict__ p1,
    const float* __restrict__ x2, const float* __restrict__ p2,
    const float* __restrict__ Wq, const float* __restrict__ Wk,
    const float* __restrict__ Wv, const float* __restrict__ Wpos,
    bf16* __restrict__ Qt, bf16* __restrict__ Kt, bf16* __restrict__ Vt) {
    __shared__ __align__(16) bf16 xp1[64 * 136];   // x1 + pos   17.4 KB
    __shared__ __align__(16) bf16 xp2[64 * 136];   // x2 + pos
    __shared__ __align__(16) bf16 xr2[64 * 136];   // x2 raw
    __shared__ float pp1[3 * 64], pp2[3 * 64], wls[384];

    const int t = threadIdx.x;
    const int b = blockIdx.y;
    const int n0 = blockIdx.x * 64;

    // ---- phase A: stage p1/p2/Wpos ----
    if (t < 48) {
        int k3 = t / 16, i4 = (t & 15) * 4;
        *(float4*)&pp1[k3 * 64 + i4] = *(const float4*)(p1 + ((size_t)b * 3 + k3) * N_ + n0 + i4);
    } else if (t < 96) {
        int tt = t - 48;
        int k3 = tt / 16, i4 = (tt & 15) * 4;
        *(float4*)&pp2[k3 * 64 + i4] = *(const float4*)(p2 + ((size_t)b * 3 + k3) * N_ + n0 + i4);
    } else if (t < 192) {
        int i4 = (t - 96) * 4;
        *(float4*)&wls[i4] = *(const float4*)(Wpos + i4);
    }
    __syncthreads();

    // ---- phase B: stage x tiles, fold pos, transpose to [n][c] bf16 ----
    for (int s = t; s < 2048; s += 768) {
        int c = s >> 4, n4 = (s & 15) * 4;
        float4 xv = *(const float4*)(x1 + ((size_t)b * C_ + c) * N_ + n0 + n4);
        float w0 = wls[c * 3 + 0], w1 = wls[c * 3 + 1], w2 = wls[c * 3 + 2];
        const float* xa = &xv.x;
        #pragma unroll
        for (int j = 0; j < 4; ++j) {
            float pos = w0 * pp1[n4 + j] + w1 * pp1[64 + n4 + j] + w2 * pp1[128 + n4 + j];
            xp1[(n4 + j) * 136 + c] = (bf16)(xa[j] + pos);
        }
    }
    for (int s = t; s < 2048; s += 768) {
        int c = s >> 4, n4 = (s & 15) * 4;
        float4 xv = *(const float4*)(x2 + ((size_t)b * C_ + c) * N_ + n0 + n4);
        float w0 = wls[c * 3 + 0], w1 = wls[c * 3 + 1], w2 = wls[c * 3 + 2];
        const float* xa = &xv.x;
        #pragma unroll
        for (int j = 0; j < 4; ++j) {
            float pos = w0 * pp2[n4 + j] + w1 * pp2[64 + n4 + j] + w2 * pp2[128 + n4 + j];
            xp2[(n4 + j) * 136 + c] = (bf16)(xa[j] + pos);
            xr2[(n4 + j) * 136 + c] = (bf16)xa[j];
        }
    }
    __syncthreads();

    // ---- phase C: MFMA per role ----
    const int w = t >> 6;
    const int lane = t & 63;
    const int col = lane & 15, quad = lane >> 4;
    const int role = w >> 2, band = w & 3;
    const int nl = band * 16 + col;
    const int n = n0 + nl;

    const bf16* src = (role == 0) ? xp1 : (role == 1) ? xp2 : xr2;
    const float* Wm = (role == 0) ? Wq : (role == 1) ? Wk : Wv;

    bf16x8 bx[4];
    #pragma unroll
    for (int cs = 0; cs < 4; ++cs)
        bx[cs] = *(const bf16x8*)&src[nl * 136 + cs * 32 + quad * 8];

    #pragma unroll
    for (int dt = 0; dt < 8; ++dt) {
        f32x4 acc = {0.f, 0.f, 0.f, 0.f};
        #pragma unroll
        for (int cs = 0; cs < 4; ++cs) {
            bf16x8 wf = cvt8(Wm + (dt * 16 + col) * 128 + cs * 32 + quad * 8);
            acc = MFMA16(wf, bx[cs], acc);
        }
        if (role < 2) {
            bf16* Ot = (role == 0) ? Qt : Kt;
            union { ushort4 u4; bf16 h[4]; } pk;
            #pragma unroll
            for (int r = 0; r < 4; ++r) pk.h[r] = (bf16)acc[r];
            *(ushort4*)(Ot + ((size_t)b * N_ + n) * C_ + dt * 16 + quad * 4) = pk.u4;
        } else {
            #pragma unroll
            for (int r = 0; r < 4; ++r)
                Vt[((size_t)b * C_ + dt * 16 + quad * 4 + r) * (size_t)M_ + n] = (bf16)acc[r];
        }
    }
}

// ===========================================================================
// Kernel 2: flash attention, block-cooperative LDS staging (the R13/R14
// bottleneck was per-wave 16-line K/V gathers: ~32 VMEM gathers/wave-iter,
// TA-bound at MfmaUtil 5%). Per 64-key chunk: stage K (64x128, stride-136)
// and V (128x64, stride-72) tiles with coalesced 16B loads; 8 waves
// (4 query-bands x 2 key-halves) consume via ds_read_b128. Next chunk is
// prefetched into registers during compute. Epilogue: R12-proven half merge,
// obuf aliased onto the staging LDS. Grid (N/64, B) = 256 blocks, 46 KB LDS.
// ===========================================================================
__global__ __launch_bounds__(512) void attn_kernel(
    const bf16* __restrict__ Qt, const bf16* __restrict__ Kt,
    const bf16* __restrict__ Vt, const float* __restrict__ x1,
    float* __restrict__ out) {
    __shared__ __align__(16) char smem[17408 + 18432 + 10240];   // 46 KB
    bf16* kb = (bf16*)smem;                    // [64 keys][136]  (c-major rows)
    bf16* vb = (bf16*)(smem + 17408);          // [128 c][72]     (key-major rows)
    bf16* pball = (bf16*)(smem + 35840);       // 8 waves x [16 q][40 keys]

    const int t = threadIdx.x;
    const int w = t >> 6;
    const int lane = t & 63;
    const int col = lane & 15, quad = lane >> 4;
    const int band = w & 3, half = w >> 2;
    const int b = blockIdx.y;
    const int n0 = blockIdx.x * 64;
    const float KS = 0.12752107168406815f;  // log2(e)/sqrt(128)

    bf16* pb = pball + w * 640;

    bf16x8 qf[4];
    {
        const bf16* Qb = Qt + ((size_t)b * N_ + n0 + band * 16 + col) * C_;
        #pragma unroll
        for (int cs = 0; cs < 4; ++cs)
            qf[cs] = *(const bf16x8*)(Qb + cs * 32 + quad * 8);
    }

    f32x4 oacc[8];
    #pragma unroll
    for (int i = 0; i < 8; ++i) oacc[i] = (f32x4){0.f, 0.f, 0.f, 0.f};
    float lacc[4] = {0.f, 0.f, 0.f, 0.f};

    // staging descriptors: 2 K segs + 2 V segs per thread (16 B each)
    const int ks0 = t, ks1 = t + 512;              // K segs: key = s>>4, off = s&15
    const int vs0 = t, vs1 = t + 512;              // V segs: c = s>>3,  off = s&7
    uint4 kreg[2], vreg[2];

    const bf16* Kbase = Kt + (size_t)b * M_ * C_;
    const bf16* Vbase = Vt + (size_t)b * C_ * M_;

    // prologue: load + store chunk 0
    {
        kreg[0] = *(const uint4*)(Kbase + (size_t)(ks0 >> 4) * C_ + (ks0 & 15) * 8);
        kreg[1] = *(const uint4*)(Kbase + (size_t)(ks1 >> 4) * C_ + (ks1 & 15) * 8);
        vreg[0] = *(const uint4*)(Vbase + (size_t)(vs0 >> 3) * M_ + (vs0 & 7) * 8);
        vreg[1] = *(const uint4*)(Vbase + (size_t)(vs1 >> 3) * M_ + (vs1 & 7) * 8);
        *(uint4*)(kb + (ks0 >> 4) * 136 + (ks0 & 15) * 8) = kreg[0];
        *(uint4*)(kb + (ks1 >> 4) * 136 + (ks1 & 15) * 8) = kreg[1];
        *(uint4*)(vb + (vs0 >> 3) * 72 + (vs0 & 7) * 8) = vreg[0];
        *(uint4*)(vb + (vs1 >> 3) * 72 + (vs1 & 7) * 8) = vreg[1];
    }
    __syncthreads();

    for (int ch = 0; ch < 64; ++ch) {
        // prefetch next chunk into registers (latency overlaps compute)
        if (ch < 63) {
            const int m1 = (ch + 1) * 64;
            kreg[0] = *(const uint4*)(Kbase + (size_t)(m1 + (ks0 >> 4)) * C_ + (ks0 & 15) * 8);
            kreg[1] = *(const uint4*)(Kbase + (size_t)(m1 + (ks1 >> 4)) * C_ + (ks1 & 15) * 8);
            vreg[0] = *(const uint4*)(Vbase + (size_t)(vs0 >> 3) * M_ + m1 + (vs0 & 7) * 8);
            vreg[1] = *(const uint4*)(Vbase + (size_t)(vs1 >> 3) * M_ + m1 + (vs1 & 7) * 8);
        }

        // ---- S = Q K^T over this wave's 32-key half ----
        f32x4 sacc[2];
        sacc[0] = (f32x4){0.f, 0.f, 0.f, 0.f};
        sacc[1] = (f32x4){0.f, 0.f, 0.f, 0.f};
        bf16x8 kf[8];
        #pragma unroll
        for (int ms = 0; ms < 2; ++ms)
            #pragma unroll
            for (int cs = 0; cs < 4; ++cs)
                kf[ms * 4 + cs] = *(const bf16x8*)&kb[(half * 32 + ms * 16 + col) * 136 + cs * 32 + quad * 8];
        #pragma unroll
        for (int ms = 0; ms < 2; ++ms)
            #pragma unroll
            for (int cs = 0; cs < 4; ++cs)
                sacc[ms] = MFMA16(qf[cs], kf[ms * 4 + cs], sacc[ms]);

        // ---- P = exp2(S*KS), row sums, stash [16q][40] ----
        #pragma unroll
        for (int ms = 0; ms < 2; ++ms)
            #pragma unroll
            for (int r = 0; r < 4; ++r) {
                float e = fminf(sacc[ms][r] * KS, 60.f);
                float pvv = __builtin_amdgcn_exp2f(e);
                lacc[r] += pvv;
                pb[(quad * 4 + r) * 40 + ms * 16 + col] = (bf16)pvv;
            }
        asm volatile("s_waitcnt lgkmcnt(0)" ::: "memory");

        bf16x8 af = *(const bf16x8*)&pb[col * 40 + quad * 8];

        // ---- O += P V^T ----
        #pragma unroll
        for (int ct = 0; ct < 8; ++ct) {
            bf16x8 vf = *(const bf16x8*)&vb[(ct * 16 + col) * 72 + half * 32 + quad * 8];
            oacc[ct] = MFMA16(af, vf, oacc[ct]);
        }

        __syncthreads();   // all waves done with kb/vb
        if (ch < 63) {
            *(uint4*)(kb + (ks0 >> 4) * 136 + (ks0 & 15) * 8) = kreg[0];
            *(uint4*)(kb + (ks1 >> 4) * 136 + (ks1 & 15) * 8) = kreg[1];
            *(uint4*)(vb + (vs0 >> 3) * 72 + (vs0 & 7) * 8) = vreg[0];
            *(uint4*)(vb + (vs1 >> 3) * 72 + (vs1 & 7) * 8) = vreg[1];
        }
        __syncthreads();   // new tile visible
    }

    // ---- denominators: reduce over the 16 key-columns ----
    #pragma unroll
    for (int r = 0; r < 4; ++r)
        #pragma unroll
        for (int off = 1; off < 16; off <<= 1)
            lacc[r] += __shfl_xor(lacc[r], off, 64);

    // ---- merge halves (obuf aliases the staging LDS; loop is done) ----
    float* obuf = (float*)smem;                 // [4 bands][16*132]
    float* lbuf = (float*)(smem + 33792);       // [4 bands][16]
    if (half == 1) {
        #pragma unroll
        for (int ct = 0; ct < 8; ++ct)
            #pragma unroll
            for (int r = 0; r < 4; ++r)
                obuf[band * 2112 + (quad * 4 + r) * 132 + ct * 16 + col] = oacc[ct][r];
        if (col == 0)
            #pragma unroll
            for (int r = 0; r < 4; ++r)
                lbuf[band * 16 + quad * 4 + r] = lacc[r];
    }
    __syncthreads();
    if (half == 0) {
        float linv[4];
        #pragma unroll
        for (int r = 0; r < 4; ++r)
            linv[r] = 1.0f / (lacc[r] + lbuf[band * 16 + quad * 4 + r]);
        #pragma unroll
        for (int ct = 0; ct < 8; ++ct) {
            #pragma unroll
            for (int r = 0; r < 4; ++r) {
                int n = n0 + band * 16 + quad * 4 + r;
                int c = ct * 16 + col;
                float o = (oacc[ct][r] + obuf[band * 2112 + (quad * 4 + r) * 132 + ct * 16 + col]) * linv[r];
                float xr = x1[((size_t)b * C_ + c) * N_ + n];
                out[((size_t)b * N_ + n) * C_ + c] = o + xr;
            }
        }
    }
}

// ---------------------------------------------------------------------------
extern "C" void kernel_launch(void* const* d_in, const int* in_sizes, int n_in,
                              void* d_out, int out_size, void* d_ws, size_t ws_size,
                              hipStream_t stream) {
    const float* x1   = (const float*)d_in[0];
    const float* p1   = (const float*)d_in[1];
    const float* x2   = (const float*)d_in[2];
    const float* p2   = (const float*)d_in[3];
    const float* Wq   = (const float*)d_in[4];
    const float* Wk   = (const float*)d_in[5];
    const float* Wv   = (const float*)d_in[6];
    const float* Wpos = (const float*)d_in[7];
    float* out = (float*)d_out;

    bf16* Qt = (bf16*)d_ws;                 // [B][N][C]
    bf16* Kt = Qt + (size_t)B_ * N_ * C_;   // [B][M][C]
    bf16* Vt = Kt + (size_t)B_ * M_ * C_;   // [B][C][M]

    proj_kernel<<<dim3(64, B_), dim3(768), 0, stream>>>(
        x1, p1, x2, p2, Wq, Wk, Wv, Wpos, Qt, Kt, Vt);
    attn_kernel<<<dim3(64, B_), dim3(512), 0, stream>>>(Qt, Kt, Vt, x1, out);
}